// Round 6
// baseline (763.717 us; speedup 1.0000x reference)
//
#include <hip/hip_runtime.h>
#include <hip/hip_fp16.h>
#include <math.h>

// ---------------- sizes ----------------
#define B32   32
#define OCLS  102
#define NCAPS 2592

// ---------------- ws map (floats) ----------------
// phase 1 (conv/pc): FEAT2 C1WB PCWB PCP U2
// phase 2 (routing): WQ2(fp8) [0,8.47M) overlays FEAT2 (dead after k_pc3)
//                    WQ (fp8) [16.93M,25.4M) overlays PCP tail (dead after squash)
// phase 3 (recon):   FC3P overlays U2+CT
#define OFF_FEAT   0u               // feat2[b][h][co][w36]: 32*34*256*36 = 10,027,008
#define OFF_WQ2    0u               // fp8 W pack [o][n][d][i]: 33,867,776 B
#define OFF_C1WT   10027008u        // bf16 conv1 pack: 3*256*128 ush
#define OFF_PCWT   10119936u        // bf16 pc pack: 256*256*104 ush
#define OFF_PCP    15428352u        // 8*32*81*256  =  5,308,416
#define OFF_WQ     16933888u        // fp8 W pack [o][n][i][d]: 33,867,776 B
#define OFF_U2     25400832u        // 32*2592*8
#define OFF_CT     26064384u        // fp16 c[o][n][b]: 8,460,288 halfs
#define OFF_FC3P   25400832u        // fc3 partials 4*32*37632 (overlay U2+CT)
#define OFF_S      30294528u        // 32*102*16
#define OFF_V0     30346752u
#define OFF_V1     30398976u
#define OFF_VSQ    30451200u        // fp8 vsum[o][b][d] x1024
#define OFF_H1     30464256u
#define OFF_H2T    30480640u        // end 30,513,408

typedef __attribute__((ext_vector_type(8))) short short8;
typedef __attribute__((ext_vector_type(4))) float f32x4;
typedef long long i64;

__device__ __forceinline__ unsigned short f2b(float f) {
  union { float f; unsigned u; } v; v.f = f;
  unsigned r = v.u + 0x7fffu + ((v.u >> 16) & 1u);
  return (unsigned short)(r >> 16);
}

// float -> OCP e4m3fn, RNE, flush |x|<2^-6 to 0, clamp >=448 to max finite
__device__ __forceinline__ unsigned f2q_fast(float x) {
  union { float f; unsigned u; } v; v.f = x;
  unsigned s = (v.u >> 24) & 0x80u;
  unsigned au = v.u & 0x7fffffffu;
  if (au < 0x3c800000u) return s;           // subnormal/zero -> 0
  if (au >= 0x43e00000u) return s | 0x7eu;  // clamp
  unsigned r = au + 0x7ffffu + ((au >> 20) & 1u);
  unsigned e = (r >> 23) - 120u;
  unsigned m = (r >> 20) & 7u;
  return s | (e << 3) | m;
}

// ---------------- conv1_w -> bf16 [ci][co][128] ----------------
__global__ void k_mkC1B(const float* __restrict__ conv1_w,
                        unsigned short* __restrict__ C1WB) {
  int co = blockIdx.x;
  int t = threadIdx.x;  // 128
#pragma unroll
  for (int ci = 0; ci < 3; ++ci) {
    float v = (t < 121) ? conv1_w[co * 363 + ci * 121 + t] : 0.f;
    C1WB[(ci * 256 + co) * 128 + t] = f2b(v);
  }
}

// ---------------- pc_w repack -> bf16 [ci][co][104] ----------------
__global__ void k_mkB(const float* __restrict__ pc_w, unsigned short* __restrict__ PCWB) {
  int co = blockIdx.x;
  for (int e = threadIdx.x; e < 20736; e += 256) {
    int ci = e / 81, tap = e - ci * 81;
    PCWB[(size_t)ci * 26624 + co * 104 + tap] = f2b(pc_w[(size_t)co * 20736 + e]);
  }
  int ci = threadIdx.x;
  for (int tap = 81; tap < 104; ++tap)
    PCWB[(size_t)ci * 26624 + co * 104 + tap] = 0;
}

// ---------------- W -> fp8 x64: Wq2[o][n][d][i] and Wq[o][n][i][d] ----------------
__global__ void k_mkW(const float* __restrict__ W, unsigned char* __restrict__ Wq2,
                      unsigned char* __restrict__ Wq) {
  int on = blockIdx.x * 256 + threadIdx.x;
  if (on >= 102 * 2592) return;
  const float4* src = (const float4*)(W + (size_t)on * 128);
  unsigned w2[32], wq[32];
#pragma unroll
  for (int j = 0; j < 32; ++j) wq[j] = 0;
#pragma unroll
  for (int d = 0; d < 16; ++d) {
    float4 a = src[d * 2], b = src[d * 2 + 1];
    float vals[8] = {a.x, a.y, a.z, a.w, b.x, b.y, b.z, b.w};
    unsigned q[8];
#pragma unroll
    for (int i = 0; i < 8; ++i) q[i] = f2q_fast(vals[i] * 64.f);
    w2[d * 2]     = q[0] | (q[1] << 8) | (q[2] << 16) | (q[3] << 24);
    w2[d * 2 + 1] = q[4] | (q[5] << 8) | (q[6] << 16) | (q[7] << 24);
#pragma unroll
    for (int i = 0; i < 8; ++i) wq[i * 4 + (d >> 2)] |= q[i] << ((d & 3) * 8);
  }
  uint4* d2 = (uint4*)(Wq2 + (size_t)on * 128);
  uint4* dq = (uint4*)(Wq + (size_t)on * 128);
#pragma unroll
  for (int k = 0; k < 8; ++k) {
    d2[k] = make_uint4(w2[4 * k], w2[4 * k + 1], w2[4 * k + 2], w2[4 * k + 3]);
    dq[k] = make_uint4(wq[4 * k], wq[4 * k + 1], wq[4 * k + 2], wq[4 * k + 3]);
  }
}

// ---------------- conv1 via bf16 MFMA implicit-im2col ----------------
__global__ __launch_bounds__(256) void k_c1m(const float* __restrict__ x,
                                             const unsigned short* __restrict__ C1WB,
                                             const float* __restrict__ bias,
                                             float* __restrict__ feat2) {
  __shared__ unsigned short sh[48 * 128 + 256 * 128];
  unsigned short* lA = sh;
  unsigned short* lB = sh + 48 * 128;
  float* obuf = (float*)(sh + 48 * 128);

  int bx = blockIdx.x;
  int b = bx / 34, ho = bx % 34;
  int t = threadIdx.x;
  int lane = t & 63, wv = t >> 6;
  int l15 = lane & 15, lh = lane >> 4;
  int rx = l15 & 7;

  {
    uint4 zz = make_uint4(0, 0, 0, 0);
    uint4* z = (uint4*)lA;
    for (int i = t; i < 48 * 128 / 8; i += 256) z[i] = zz;
  }
  __syncthreads();

  f32x4 acc[3][4];
#pragma unroll
  for (int mf = 0; mf < 3; ++mf)
#pragma unroll
    for (int nf = 0; nf < 4; ++nf) acc[mf][nf] = (f32x4){0.f, 0.f, 0.f, 0.f};

#pragma unroll 1
  for (int ci = 0; ci < 3; ++ci) {
    {
      const uint4* Bsrc = (const uint4*)(C1WB + ci * 32768);
#pragma unroll
      for (int i = 0; i < 16; ++i) {
        int f = i * 256 + t;
        int row = f >> 4, cu = f & 15;
        ((uint4*)lB)[row * 16 + (cu ^ (row & 7))] = Bsrc[f];
      }
    }
    for (int tk = t; tk < 374; tk += 256) {
      int kh = tk / 34, wo = tk - kh * 34;
      const float* src = x + ((size_t)(b * 3 + ci) * 112 + ho * 3 + kh) * 112 + wo * 3;
#pragma unroll
      for (int j = 0; j < 11; ++j) {
        int tap = kh * 11 + j;
        int cu = tap >> 3;
        lA[wo * 128 + (((cu ^ (wo & 7)) << 3) | (tap & 7))] = f2b(src[j]);
      }
    }
    __syncthreads();

#pragma unroll
    for (int s = 0; s < 4; ++s) {
      int cub = ((s * 4 + lh) ^ rx) << 3;
      short8 a0 = *(const short8*)(lA + (0 + l15) * 128 + cub);
      short8 a1 = *(const short8*)(lA + (16 + l15) * 128 + cub);
      short8 a2 = *(const short8*)(lA + (32 + l15) * 128 + cub);
      short8 b0 = *(const short8*)(lB + (wv * 64 + 0 + l15) * 128 + cub);
      short8 b1 = *(const short8*)(lB + (wv * 64 + 16 + l15) * 128 + cub);
      short8 b2 = *(const short8*)(lB + (wv * 64 + 32 + l15) * 128 + cub);
      short8 b3 = *(const short8*)(lB + (wv * 64 + 48 + l15) * 128 + cub);
      acc[0][0] = __builtin_amdgcn_mfma_f32_16x16x32_bf16(a0, b0, acc[0][0], 0, 0, 0);
      acc[0][1] = __builtin_amdgcn_mfma_f32_16x16x32_bf16(a0, b1, acc[0][1], 0, 0, 0);
      acc[0][2] = __builtin_amdgcn_mfma_f32_16x16x32_bf16(a0, b2, acc[0][2], 0, 0, 0);
      acc[0][3] = __builtin_amdgcn_mfma_f32_16x16x32_bf16(a0, b3, acc[0][3], 0, 0, 0);
      acc[1][0] = __builtin_amdgcn_mfma_f32_16x16x32_bf16(a1, b0, acc[1][0], 0, 0, 0);
      acc[1][1] = __builtin_amdgcn_mfma_f32_16x16x32_bf16(a1, b1, acc[1][1], 0, 0, 0);
      acc[1][2] = __builtin_amdgcn_mfma_f32_16x16x32_bf16(a1, b2, acc[1][2], 0, 0, 0);
      acc[1][3] = __builtin_amdgcn_mfma_f32_16x16x32_bf16(a1, b3, acc[1][3], 0, 0, 0);
      acc[2][0] = __builtin_amdgcn_mfma_f32_16x16x32_bf16(a2, b0, acc[2][0], 0, 0, 0);
      acc[2][1] = __builtin_amdgcn_mfma_f32_16x16x32_bf16(a2, b1, acc[2][1], 0, 0, 0);
      acc[2][2] = __builtin_amdgcn_mfma_f32_16x16x32_bf16(a2, b2, acc[2][2], 0, 0, 0);
      acc[2][3] = __builtin_amdgcn_mfma_f32_16x16x32_bf16(a2, b3, acc[2][3], 0, 0, 0);
    }
    __syncthreads();
  }

  float bv[4];
#pragma unroll
  for (int nf = 0; nf < 4; ++nf) bv[nf] = bias[wv * 64 + nf * 16 + l15];
#pragma unroll
  for (int mf = 0; mf < 3; ++mf)
#pragma unroll
    for (int nf = 0; nf < 4; ++nf)
#pragma unroll
      for (int r = 0; r < 4; ++r) {
        int wo = mf * 16 + lh * 4 + r;
        if (wo < 36)
          obuf[(wv * 64 + nf * 16 + l15) * 36 + wo] = fmaxf(acc[mf][nf][r] + bv[nf], 0.f);
      }
  __syncthreads();
  float4* dst = (float4*)(feat2 + (size_t)bx * 9216);
  const float4* srcb = (const float4*)obuf;
#pragma unroll
  for (int i = 0; i < 9; ++i) dst[i * 256 + t] = srcb[i * 256 + t];
}

// ---------------- pc conv gather helper ----------------
__device__ __forceinline__ void pc_gather(const float* __restrict__ feat2,
                                          unsigned short* __restrict__ dstbuf,
                                          int mb, int ci, int t) {
  for (int task = t; task < 576; task += 256) {
    int m = task / 9, kh = task - m * 9;
    int gm = mb * 64 + m;
    if (gm < 2592) {
      int b = gm / 81, p = gm - b * 81;
      int ho = p / 9, wo = p - ho * 9;
      const float* src = feat2 + ((size_t)(b * 34 + ho * 3 + kh) * 256 + ci) * 36 + wo * 3;
      unsigned short* dst = dstbuf + m * 104 + kh * 9;
#pragma unroll
      for (int j = 0; j < 9; ++j) dst[j] = f2b(src[j]);
    }
  }
}

// ---------------- primary caps conv: B-in-regs, A dbuf in LDS ----------------
__global__ __launch_bounds__(256, 3) void k_pc3(const float* __restrict__ feat2,
                                                const unsigned short* __restrict__ PCWB,
                                                float* __restrict__ pcp) {
  __shared__ unsigned short lA[2][64 * 104];

  int mb = blockIdx.x, kc = blockIdx.y;
  int t = threadIdx.x;
  int lane = t & 63, wv = t >> 6;
  int l15 = lane & 15, lh = lane >> 4;

  {
    uint4 zz = make_uint4(0, 0, 0, 0);
    uint4* z = (uint4*)lA;
    for (int i = t; i < 2 * 64 * 104 / 8; i += 256) z[i] = zz;
  }
  __syncthreads();
  pc_gather(feat2, lA[0], mb, kc * 32, t);
  __syncthreads();

  f32x4 acc[4][4];
#pragma unroll
  for (int mf = 0; mf < 4; ++mf)
#pragma unroll
    for (int nf = 0; nf < 4; ++nf) acc[mf][nf] = (f32x4){0.f, 0.f, 0.f, 0.f};

#pragma unroll 1
  for (int cil = 0; cil < 32; ++cil) {
    int ci = kc * 32 + cil;
    int cur = cil & 1;

    // B fragments straight from global (L2-hot), no LDS
    short8 bfr[4][3];
    const unsigned short* Bbase = PCWB + (size_t)ci * 26624 + (wv * 64 + l15) * 104 + lh * 8;
#pragma unroll
    for (int nf = 0; nf < 4; ++nf)
#pragma unroll
      for (int s = 0; s < 3; ++s)
        bfr[nf][s] = *(const short8*)(Bbase + nf * 16 * 104 + s * 32);

    // prefetch next A tile into other buffer
    if (cil < 31) pc_gather(feat2, lA[cur ^ 1], mb, ci + 1, t);

    const unsigned short* arow = lA[cur] + l15 * 104 + lh * 8;
#pragma unroll
    for (int s = 0; s < 3; ++s) {
      short8 a0 = *(const short8*)(arow + s * 32);
      short8 a1 = *(const short8*)(arow + 16 * 104 + s * 32);
      short8 a2 = *(const short8*)(arow + 32 * 104 + s * 32);
      short8 a3 = *(const short8*)(arow + 48 * 104 + s * 32);
      acc[0][0] = __builtin_amdgcn_mfma_f32_16x16x32_bf16(a0, bfr[0][s], acc[0][0], 0, 0, 0);
      acc[0][1] = __builtin_amdgcn_mfma_f32_16x16x32_bf16(a0, bfr[1][s], acc[0][1], 0, 0, 0);
      acc[0][2] = __builtin_amdgcn_mfma_f32_16x16x32_bf16(a0, bfr[2][s], acc[0][2], 0, 0, 0);
      acc[0][3] = __builtin_amdgcn_mfma_f32_16x16x32_bf16(a0, bfr[3][s], acc[0][3], 0, 0, 0);
      acc[1][0] = __builtin_amdgcn_mfma_f32_16x16x32_bf16(a1, bfr[0][s], acc[1][0], 0, 0, 0);
      acc[1][1] = __builtin_amdgcn_mfma_f32_16x16x32_bf16(a1, bfr[1][s], acc[1][1], 0, 0, 0);
      acc[1][2] = __builtin_amdgcn_mfma_f32_16x16x32_bf16(a1, bfr[2][s], acc[1][2], 0, 0, 0);
      acc[1][3] = __builtin_amdgcn_mfma_f32_16x16x32_bf16(a1, bfr[3][s], acc[1][3], 0, 0, 0);
      acc[2][0] = __builtin_amdgcn_mfma_f32_16x16x32_bf16(a2, bfr[0][s], acc[2][0], 0, 0, 0);
      acc[2][1] = __builtin_amdgcn_mfma_f32_16x16x32_bf16(a2, bfr[1][s], acc[2][1], 0, 0, 0);
      acc[2][2] = __builtin_amdgcn_mfma_f32_16x16x32_bf16(a2, bfr[2][s], acc[2][2], 0, 0, 0);
      acc[2][3] = __builtin_amdgcn_mfma_f32_16x16x32_bf16(a2, bfr[3][s], acc[2][3], 0, 0, 0);
      acc[3][0] = __builtin_amdgcn_mfma_f32_16x16x32_bf16(a3, bfr[0][s], acc[3][0], 0, 0, 0);
      acc[3][1] = __builtin_amdgcn_mfma_f32_16x16x32_bf16(a3, bfr[1][s], acc[3][1], 0, 0, 0);
      acc[3][2] = __builtin_amdgcn_mfma_f32_16x16x32_bf16(a3, bfr[2][s], acc[3][2], 0, 0, 0);
      acc[3][3] = __builtin_amdgcn_mfma_f32_16x16x32_bf16(a3, bfr[3][s], acc[3][3], 0, 0, 0);
    }
    __syncthreads();
  }

#pragma unroll
  for (int mf = 0; mf < 4; ++mf) {
    int gm = mb * 64 + mf * 16 + lh * 4;
    if (gm < 2592) {
      float* dst = pcp + (size_t)kc * 663552 + (size_t)gm * 256 + wv * 64 + l15;
#pragma unroll
      for (int nf = 0; nf < 4; ++nf)
#pragma unroll
        for (int r = 0; r < 4; ++r)
          dst[(size_t)r * 256 + nf * 16] = acc[mf][nf][r];
    }
  }
}

// ---------------- fused: sum 8 partials + bias + squash -> u2[b][n][i] ----------------
__global__ void k_squash2(const float* __restrict__ pcp, const float* __restrict__ pcb,
                          float* __restrict__ u2) {
  int t = blockIdx.x * 256 + threadIdx.x;  // < 82944
  int b = t / 2592, n = t - b * 2592;
  float v[8];
  float sq = 0.f;
#pragma unroll
  for (int i = 0; i < 8; ++i) {
    int f = n * 8 + i;
    int co = f / 81, p = f - co * 81;
    const float* base = pcp + (size_t)(b * 81 + p) * 256 + co;
    float s = pcb[co];
#pragma unroll
    for (int c = 0; c < 8; ++c) s += base[(size_t)c * 663552];
    v[i] = s;
    sq += s * s;
  }
  float sc = (sq / (1.f + sq)) / sqrtf(sq + 1e-8f);
#pragma unroll
  for (int i = 0; i < 8; ++i) u2[t * 8 + i] = v[i] * sc;
}

// ---------------- routing kernel A (fp8 MFMA): logits + softmax -> cT ----------------
__global__ __launch_bounds__(128) void k_A2(const unsigned char* __restrict__ Wq,
                                            const float* __restrict__ u2,
                                            const unsigned char* __restrict__ vq,
                                            __half* __restrict__ cT) {
  __shared__ __half Eld[102 * 2 * 2 * 32];
  int nb = blockIdx.x;  // 648
  int t = threadIdx.x, wv = t >> 6, lane = t & 63;
  int l15 = lane & 15, g = lane >> 4;
  int n0 = nb * 4 + 2 * wv;
  int nl = g >> 1, ih = (g & 1) * 4;

  float4 u0 = *(const float4*)(u2 + (((size_t)l15 * 2592 + n0 + nl) * 8 + ih));
  float4 u1 = *(const float4*)(u2 + (((size_t)(l15 + 16) * 2592 + n0 + nl) * 8 + ih));

  int nlA = l15 >> 3, iA = l15 & 7;
  const unsigned char* Ap = Wq + (((size_t)(n0 + nlA)) * 8 + iA) * 16 + (g & 1) * 8;
  const unsigned char* B0p = vq + (size_t)l15 * 16 + (g & 1) * 8;
  bool act = (g < 2);

  float den0 = 0.f, den1 = 0.f;
#pragma unroll 2
  for (int o = 0; o < 102; ++o) {
    i64 a = 0, b0 = 0, b1 = 0;
    if (act) {
      a  = *(const i64*)(Ap + (size_t)o * 331776);
      b0 = *(const i64*)(B0p + (size_t)o * 512);
      b1 = *(const i64*)(B0p + (size_t)o * 512 + 256);
    }
    f32x4 d0 = {0.f, 0.f, 0.f, 0.f}, d1 = {0.f, 0.f, 0.f, 0.f};
    d0 = __builtin_amdgcn_mfma_f32_16x16x32_fp8_fp8(a, b0, d0, 0, 0, 0);
    d1 = __builtin_amdgcn_mfma_f32_16x16x32_fp8_fp8(a, b1, d1, 0, 0, 0);
    float p0 = d0[0] * u0.x + d0[1] * u0.y + d0[2] * u0.z + d0[3] * u0.w;
    float p1 = d1[0] * u1.x + d1[1] * u1.y + d1[2] * u1.z + d1[3] * u1.w;
    p0 += __shfl_xor(p0, 16);
    p1 += __shfl_xor(p1, 16);
    p0 *= 1.52587890625e-05f;  // / (64 * 1024)
    p1 *= 1.52587890625e-05f;
    float e0 = __expf(p0), e1 = __expf(p1);
    den0 += e0; den1 += e1;
    if ((g & 1) == 0) {
      int base = (o * 2 + wv) * 64 + (g >> 1) * 16 + l15;
      Eld[base] = __float2half(e0);
      Eld[base + 32] = __float2half(e1);
    }
  }
  float r0 = 1.0f / den0, r1 = 1.0f / den1;
  if ((g & 1) == 0) {
    for (int o = 0; o < 102; ++o) {
      int base = (o * 2 + wv) * 64 + (g >> 1) * 16 + l15;
      float c0 = __half2float(Eld[base]) * r0;
      float c1 = __half2float(Eld[base + 32]) * r1;
      __half* dst = cT + ((size_t)o * 2592 + n0 + (g >> 1)) * 32 + l15;
      dst[0] = __float2half(c0);
      dst[16] = __float2half(c1);
    }
  }
}

// ---------------- routing kernel B (fp8 MFMA): s = sum c*xhat ----------------
__device__ __forceinline__ i64 cu_pack8(float c16, float4 a, float4 b) {
  unsigned lo = f2q_fast(c16 * a.x) | (f2q_fast(c16 * a.y) << 8) |
                (f2q_fast(c16 * a.z) << 16) | (f2q_fast(c16 * a.w) << 24);
  unsigned hi = f2q_fast(c16 * b.x) | (f2q_fast(c16 * b.y) << 8) |
                (f2q_fast(c16 * b.z) << 16) | (f2q_fast(c16 * b.w) << 24);
  union { unsigned u[2]; i64 v; } r;
  r.u[0] = lo; r.u[1] = hi;
  return r.v;
}

template <bool HASC>
__global__ __launch_bounds__(256) void k_B3(const unsigned char* __restrict__ Wq2,
                                            const float* __restrict__ u2,
                                            const __half* __restrict__ cT,
                                            float* __restrict__ s) {
  int o = blockIdx.x, kc = blockIdx.y;
  int t = threadIdx.x, lane = t & 63, wv = t >> 6;
  int l15 = lane & 15, h = lane >> 4;

  f32x4 acc0 = {0.f, 0.f, 0.f, 0.f}, acc1 = {0.f, 0.f, 0.f, 0.f};

#pragma unroll 1
  for (int st = wv; st < 81; st += 4) {
    int n = kc * 324 + st * 4 + h;
    i64 aq = *(const i64*)(Wq2 + (((size_t)o * 2592 + n) * 16 + l15) * 8);

    const float4* u0p = (const float4*)(u2 + ((size_t)l15 * 2592 + n) * 8);
    float4 u0a = u0p[0], u0b = u0p[1];
    const float4* u1p = (const float4*)(u2 + ((size_t)(l15 + 16) * 2592 + n) * 8);
    float4 u1a = u1p[0], u1b = u1p[1];

    float c0 = 16.0f, c1 = 16.0f;
    if (HASC) {
      const __half* cp = cT + ((size_t)o * 2592 + n) * 32;
      c0 = 16.0f * __half2float(cp[l15]);
      c1 = 16.0f * __half2float(cp[l15 + 16]);
    }
    i64 b0 = cu_pack8(c0, u0a, u0b);
    i64 b1 = cu_pack8(c1, u1a, u1b);

    acc0 = __builtin_amdgcn_mfma_f32_16x16x32_fp8_fp8(aq, b0, acc0, 0, 0, 0);
    acc1 = __builtin_amdgcn_mfma_f32_16x16x32_fp8_fp8(aq, b1, acc1, 0, 0, 0);
  }

#pragma unroll
  for (int r = 0; r < 4; ++r) {
    atomicAdd(s + ((size_t)l15 * 102 + o) * 16 + h * 4 + r, acc0[r]);
    atomicAdd(s + ((size_t)(l15 + 16) * 102 + o) * 16 + h * 4 + r, acc1[r]);
  }
}

// ---------------- squash v (dim 16); optional fp8 vsum (x1024) ----------------
__global__ void k_R(const float* __restrict__ s, float scale,
                    float* __restrict__ vout, const float* __restrict__ addin,
                    unsigned char* __restrict__ vsq) {
  int t = blockIdx.x * 256 + threadIdx.x;
  if (t >= 3264) return;
  const float* sp = s + t * 16;
  float r[16];
  float sq = 0.f;
#pragma unroll
  for (int d = 0; d < 16; ++d) {
    r[d] = sp[d] * scale;
    sq += r[d] * r[d];
  }
  float sc = (sq / (1.f + sq)) / sqrtf(sq + 1e-8f);
  float vv[16];
#pragma unroll
  for (int d = 0; d < 16; ++d) {
    vv[d] = r[d] * sc;
    vout[t * 16 + d] = vv[d];
  }
  if (vsq) {
    int b = t / 102, o = t - b * 102;
    unsigned words[4] = {0, 0, 0, 0};
#pragma unroll
    for (int d = 0; d < 16; ++d) {
      float w = addin ? (addin[t * 16 + d] + vv[d]) : vv[d];
      words[d >> 2] |= f2q_fast(w * 1024.f) << ((d & 3) * 8);
    }
    *(uint4*)(vsq + ((size_t)o * 32 + b) * 16) =
        make_uint4(words[0], words[1], words[2], words[3]);
  }
}

// ---------------- fc chain ----------------
__global__ void k_fc1(const float* __restrict__ v2, const int* __restrict__ tgt,
                      const float* __restrict__ w1, const float* __restrict__ b1,
                      float* __restrict__ h1) {
  int j = blockIdx.x * 128 + threadIdx.x;
  int bq = blockIdx.y;
#pragma unroll
  for (int bi = 0; bi < 4; ++bi) {
    int b = bq * 4 + bi;
    int tb = tgt[b];
    float acc = b1[j];
    const float* vv = v2 + (b * 102 + tb) * 16;
    const float* wr = w1 + (tb * 16) * 512 + j;
#pragma unroll
    for (int d = 0; d < 16; ++d) acc += vv[d] * wr[d * 512];
    h1[b * 512 + j] = fmaxf(acc, 0.f);
  }
}

__global__ void k_fc2(const float* __restrict__ h1, const float* __restrict__ w2,
                      const float* __restrict__ b2, float* __restrict__ h2T) {
  int j = blockIdx.x * 128 + threadIdx.x;
  int bq = blockIdx.y;
  float acc[4];
#pragma unroll
  for (int bi = 0; bi < 4; ++bi) acc[bi] = b2[j];
  for (int k = 0; k < 512; ++k) {
    float wv = w2[k * 1024 + j];
#pragma unroll
    for (int bi = 0; bi < 4; ++bi) acc[bi] += h1[(bq * 4 + bi) * 512 + k] * wv;
  }
  float4 o;
  o.x = fmaxf(acc[0], 0.f); o.y = fmaxf(acc[1], 0.f);
  o.z = fmaxf(acc[2], 0.f); o.w = fmaxf(acc[3], 0.f);
  *(float4*)(h2T + j * 32 + bq * 4) = o;
}

__global__ void k_fc3a(const float* __restrict__ h2T, const float* __restrict__ w3,
                       float* __restrict__ p) {
  int j = blockIdx.x * 128 + threadIdx.x;
  int ky = blockIdx.y;
  float acc[32];
#pragma unroll
  for (int i = 0; i < 32; ++i) acc[i] = 0.f;
  int k0 = ky * 256;
  for (int k = k0; k < k0 + 256; ++k) {
    float wv = w3[(size_t)k * 37632 + j];
    const float4* hp = (const float4*)(h2T + k * 32);
#pragma unroll
    for (int q = 0; q < 8; ++q) {
      float4 h = hp[q];
      acc[q * 4 + 0] += h.x * wv; acc[q * 4 + 1] += h.y * wv;
      acc[q * 4 + 2] += h.z * wv; acc[q * 4 + 3] += h.w * wv;
    }
  }
#pragma unroll
  for (int i = 0; i < 32; ++i)
    p[((size_t)ky * 32 + i) * 37632 + j] = acc[i];
}

__global__ void k_fc3b(const float* __restrict__ p, const float* __restrict__ b3,
                       float* __restrict__ out) {
  int j = blockIdx.x * 256 + threadIdx.x;
  float bv = b3[j];
#pragma unroll 1
  for (int b = 0; b < 32; ++b) {
    float s = bv + p[(size_t)b * 37632 + j] + p[(size_t)(32 + b) * 37632 + j] +
              p[(size_t)(64 + b) * 37632 + j] + p[(size_t)(96 + b) * 37632 + j];
    out[52224 + (size_t)b * 37632 + j] = 1.0f / (1.0f + __expf(-s));
  }
}

// ---------------- host ----------------
extern "C" void kernel_launch(void* const* d_in, const int* in_sizes, int n_in,
                              void* d_out, int out_size, void* d_ws, size_t ws_size,
                              hipStream_t stream) {
  const float* x       = (const float*)d_in[0];
  const int*   targets = (const int*)d_in[1];
  const float* conv1_w = (const float*)d_in[2];
  const float* conv1_b = (const float*)d_in[3];
  const float* pc_w    = (const float*)d_in[4];
  const float* pc_b    = (const float*)d_in[5];
  const float* W       = (const float*)d_in[6];
  const float* fc1_w   = (const float*)d_in[7];
  const float* fc1_b   = (const float*)d_in[8];
  const float* fc2_w   = (const float*)d_in[9];
  const float* fc2_b   = (const float*)d_in[10];
  const float* fc3_w   = (const float*)d_in[11];
  const float* fc3_b   = (const float*)d_in[12];
  float* out = (float*)d_out;
  float* ws = (float*)d_ws;

  float* FEAT2 = ws + OFF_FEAT;
  unsigned short* C1WB = (unsigned short*)(ws + OFF_C1WT);
  unsigned short* PCWB = (unsigned short*)(ws + OFF_PCWT);
  float* PCP  = ws + OFF_PCP;
  float* U2   = ws + OFF_U2;
  unsigned char* WQ2 = (unsigned char*)(ws + OFF_WQ2);  // overlays FEAT2 after k_pc3
  unsigned char* WQ  = (unsigned char*)(ws + OFF_WQ);   // overlays PCP tail after squash
  __half* CT  = (__half*)(ws + OFF_CT);
  float* FC3P = ws + OFF_FC3P;
  float* S    = ws + OFF_S;
  float* V0   = ws + OFF_V0;
  float* V1   = ws + OFF_V1;
  unsigned char* VSQ = (unsigned char*)(ws + OFF_VSQ);
  float* H1   = ws + OFF_H1;
  float* H2T  = ws + OFF_H2T;

  // weight prep (conv phase)
  k_mkC1B<<<dim3(256), 128, 0, stream>>>(conv1_w, C1WB);
  k_mkB<<<dim3(256), 256, 0, stream>>>(pc_w, PCWB);

  // conv1 + relu (bf16 MFMA)
  k_c1m<<<dim3(1088), 256, 0, stream>>>(x, C1WB, conv1_b, FEAT2);

  // primary caps conv + fused reduce/bias/squash
  k_pc3<<<dim3(41, 8), 256, 0, stream>>>(FEAT2, PCWB, PCP);
  k_squash2<<<dim3(324), 256, 0, stream>>>(PCP, pc_b, U2);

  // routing pack: W read once -> two fp8 layouts (x64)
  k_mkW<<<dim3(1033), 256, 0, stream>>>(W, WQ2, WQ);

  // ---- routing ---- (acc scale: W x64, cu x16 -> /1024; vq x1024, logits /65536)
  hipMemsetAsync(S, 0, 52224 * sizeof(float), stream);
  k_B3<false><<<dim3(102, 8), 256, 0, stream>>>(WQ2, U2, nullptr, S);
  k_R<<<dim3(13), 256, 0, stream>>>(S, 1.0f / (102.0f * 1024.0f), V0, nullptr, VSQ);

  k_A2<<<dim3(648), 128, 0, stream>>>(WQ, U2, VSQ, CT);
  hipMemsetAsync(S, 0, 52224 * sizeof(float), stream);
  k_B3<true><<<dim3(102, 8), 256, 0, stream>>>(WQ2, U2, CT, S);
  k_R<<<dim3(13), 256, 0, stream>>>(S, 1.0f / 1024.0f, V1, V0, VSQ);  // vsq = v0+v1

  k_A2<<<dim3(648), 128, 0, stream>>>(WQ, U2, VSQ, CT);
  hipMemsetAsync(S, 0, 52224 * sizeof(float), stream);
  k_B3<true><<<dim3(102, 8), 256, 0, stream>>>(WQ2, U2, CT, S);
  k_R<<<dim3(13), 256, 0, stream>>>(S, 1.0f / 1024.0f, out, nullptr, nullptr);

  // ---- reconstruction ----
  k_fc1<<<dim3(4, 8), 128, 0, stream>>>(out, targets, fc1_w, fc1_b, H1);
  k_fc2<<<dim3(8, 8), 128, 0, stream>>>(H1, fc2_w, fc2_b, H2T);
  k_fc3a<<<dim3(294, 4), 128, 0, stream>>>(H2T, fc3_w, FC3P);
  k_fc3b<<<dim3(147), 256, 0, stream>>>(FC3P, fc3_b, out);
}